// Round 1
// baseline (495.708 us; speedup 1.0000x reference)
//
#include <hip/hip_runtime.h>

// Discriminator GCN: x2 = sigmoid(GCN2(sigmoid(GCN1(x)))), N=4096, E=262144.
// Strategy: densify S = D^-1/2 (A+I) D^-1/2 (4096x4096, 1.6% dense) and do both
// layer-1 steps as bf16 MFMA GEMMs:
//   GEMM1: H1T = GEMM(A=W1^T, BT=x)      -> H1T[j][i] = (x@W1)[i][j]
//   GEMM2: X1  = GEMM(A=S,    BT=H1T)    -> sigmoid(S@(x@W1) + b1)
// Layer 2 (W2 is [4096,1]) = matvec + scalar edge aggregation.
// Workspace need: 128MB + 64KB.

typedef __attribute__((ext_vector_type(8))) short bf16x8;   // 8 bf16 (4 VGPRs)
typedef __attribute__((ext_vector_type(4))) float f32x4;

#define NN 4096

__device__ __forceinline__ unsigned f2bf(float f) {
  unsigned u = __float_as_uint(f);
  return (u + 0x7FFFu + ((u >> 16) & 1u)) >> 16;   // RNE f32 -> bf16
}

// ---------------- small graph kernels ----------------

__global__ void init_deg_kernel(float* deg) {
  int v = blockIdx.x * 256 + threadIdx.x;
  if (v < NN) deg[v] = 1.0f;                        // self loop
}

__global__ void count_deg_kernel(const int* __restrict__ dst, int E, float* deg) {
  int e = blockIdx.x * 256 + threadIdx.x;
  if (e < E) atomicAdd(&deg[dst[e]], 1.0f);
}

__global__ void dinv_kernel(const float* __restrict__ deg, float* __restrict__ dinv) {
  int v = blockIdx.x * 256 + threadIdx.x;
  if (v < NN) dinv[v] = rsqrtf(deg[v]);             // deg >= 1 always
}

__global__ void diag_kernel(const float* __restrict__ dinv, float* __restrict__ S) {
  int v = blockIdx.x * 256 + threadIdx.x;
  if (v < NN) { float d = dinv[v]; S[(size_t)v * NN + v] = d * d; }
}

__global__ void scatter_S_kernel(const int* __restrict__ src, const int* __restrict__ dst,
                                 int E, const float* __restrict__ dinv, float* __restrict__ S) {
  int e = blockIdx.x * 256 + threadIdx.x;
  if (e < E) {
    int s = src[e], d = dst[e];
    atomicAdd(&S[(size_t)d * NN + s], dinv[s] * dinv[d]);  // duplicates must sum
  }
}

// ---------------- casts ----------------

__global__ void cast_kernel(const float* __restrict__ in, unsigned short* __restrict__ out, int n) {
  int i = (blockIdx.x * 256 + threadIdx.x) * 8;
  if (i >= n) return;
  const float4* p = (const float4*)(in + i);
  float4 a = p[0], b = p[1];
  uint4 o;
  o.x = f2bf(a.x) | (f2bf(a.y) << 16);
  o.y = f2bf(a.z) | (f2bf(a.w) << 16);
  o.z = f2bf(b.x) | (f2bf(b.y) << 16);
  o.w = f2bf(b.z) | (f2bf(b.w) << 16);
  *(uint4*)(out + i) = o;
}

__global__ void transpose_cast_kernel(const float* __restrict__ W, unsigned short* __restrict__ WT) {
  __shared__ float tile[32][33];
  int bx = blockIdx.x * 32, by = blockIdx.y * 32;
  int tx = threadIdx.x, ty = threadIdx.y;   // 32x8
#pragma unroll
  for (int i = 0; i < 32; i += 8)
    tile[ty + i][tx] = W[(size_t)(by + ty + i) * NN + bx + tx];
  __syncthreads();
#pragma unroll
  for (int i = 0; i < 32; i += 8)
    WT[(size_t)(bx + ty + i) * NN + by + tx] = (unsigned short)f2bf(tile[tx][ty + i]);
}

// ---------------- bf16 MFMA GEMM: C[M][N] = A[M][K] * BT[N][K]^T ----------------
// 128x128 tile, BK=32, 4 waves each computing a 64x64 quadrant (4x4 16x16 frags).

#define GL16(g, l) __builtin_amdgcn_global_load_lds(                      \
    (const __attribute__((address_space(1))) void*)(g),                   \
    (__attribute__((address_space(3))) void*)(l), 16, 0, 0)

template <int EPI>  // 0: bf16 store; 1: +bias, sigmoid, bf16 store
__global__ __launch_bounds__(256) void gemm_bt_kernel(
    const unsigned short* __restrict__ A, const unsigned short* __restrict__ BT,
    unsigned short* __restrict__ C, const float* __restrict__ bias) {
  __shared__ __align__(16) unsigned short lA[128 * 32];
  __shared__ __align__(16) unsigned short lB[128 * 32];
  const int t = threadIdx.x;
  const int lane = t & 63, wid = t >> 6;
  const int wr = wid >> 1, wc = wid & 1;
  const int rowBase = blockIdx.y * 128, colBase = blockIdx.x * 128;

  f32x4 acc[4][4] = {};

  const unsigned short* Ag = A + (size_t)(rowBase + (t >> 2)) * NN + (t & 3) * 8;
  const unsigned short* Bg = BT + (size_t)(colBase + (t >> 2)) * NN + (t & 3) * 8;
  char* lAw = (char*)lA + wid * 1024;   // wave-uniform LDS dest (HW adds lane*16)
  char* lBw = (char*)lB + wid * 1024;

  for (int k0 = 0; k0 < NN; k0 += 32) {
    GL16(Ag + k0, lAw);
    GL16(Ag + k0 + (size_t)64 * NN, lAw + 4096);
    GL16(Bg + k0, lBw);
    GL16(Bg + k0 + (size_t)64 * NN, lBw + 4096);
    __syncthreads();   // compiler drains vmcnt before barrier

    bf16x8 af[4], bfr[4];
#pragma unroll
    for (int m = 0; m < 4; ++m)
      af[m] = *(const bf16x8*)(lA + (wr * 64 + m * 16 + (lane & 15)) * 32 + (lane >> 4) * 8);
#pragma unroll
    for (int n = 0; n < 4; ++n)
      bfr[n] = *(const bf16x8*)(lB + (wc * 64 + n * 16 + (lane & 15)) * 32 + (lane >> 4) * 8);
#pragma unroll
    for (int m = 0; m < 4; ++m)
#pragma unroll
      for (int n = 0; n < 4; ++n)
        acc[m][n] = __builtin_amdgcn_mfma_f32_16x16x32_bf16(af[m], bfr[n], acc[m][n], 0, 0, 0);
    __syncthreads();
  }

  const int orow = rowBase + wr * 64 + (lane >> 4) * 4;
  const int ocol = colBase + wc * 64 + (lane & 15);
#pragma unroll
  for (int n = 0; n < 4; ++n) {
    int c = ocol + n * 16;
    float bv = (EPI == 1) ? bias[c] : 0.0f;
#pragma unroll
    for (int m = 0; m < 4; ++m) {
#pragma unroll
      for (int i = 0; i < 4; ++i) {
        float x = acc[m][n][i] + bv;
        if (EPI == 1) x = 1.0f / (1.0f + __expf(-x));
        C[(size_t)(orow + m * 16 + i) * NN + c] = (unsigned short)f2bf(x);
      }
    }
  }
}

// ---------------- layer 2 ----------------

__global__ void matvec_kernel(const unsigned short* __restrict__ X1,
                              const float* __restrict__ W2, float* __restrict__ h2) {
  int row = blockIdx.x, t = threadIdx.x;
  const unsigned short* xr = X1 + (size_t)row * NN;
  float s = 0.0f;
  for (int j = t * 8; j < NN; j += 2048) {
    uint4 u = *(const uint4*)(xr + j);
    unsigned v[4] = {u.x, u.y, u.z, u.w};
#pragma unroll
    for (int q = 0; q < 4; ++q) {
      float lo = __uint_as_float(v[q] << 16);
      float hi = __uint_as_float(v[q] & 0xFFFF0000u);
      s += lo * W2[j + q * 2] + hi * W2[j + q * 2 + 1];
    }
  }
#pragma unroll
  for (int off = 32; off > 0; off >>= 1) s += __shfl_down(s, off);
  __shared__ float wsum[4];
  if ((t & 63) == 0) wsum[t >> 6] = s;
  __syncthreads();
  if (t == 0) h2[row] = wsum[0] + wsum[1] + wsum[2] + wsum[3];
}

__global__ void init_t_kernel(const float* __restrict__ dinv, const float* __restrict__ h2,
                              const float* __restrict__ b2, float* __restrict__ tacc) {
  int v = blockIdx.x * 256 + threadIdx.x;
  if (v < NN) tacc[v] = dinv[v] * dinv[v] * h2[v] + b2[0];
}

__global__ void scatter_t_kernel(const int* __restrict__ src, const int* __restrict__ dst,
                                 int E, const float* __restrict__ dinv,
                                 const float* __restrict__ h2, float* __restrict__ tacc) {
  int e = blockIdx.x * 256 + threadIdx.x;
  if (e < E) {
    int s = src[e], d = dst[e];
    atomicAdd(&tacc[d], dinv[s] * dinv[d] * h2[s]);
  }
}

__global__ void final_kernel(const float* __restrict__ tacc, float* __restrict__ out) {
  int v = blockIdx.x * 256 + threadIdx.x;
  if (v < NN) out[v] = 1.0f / (1.0f + __expf(-tacc[v]));
}

// ---------------- launch ----------------

extern "C" void kernel_launch(void* const* d_in, const int* in_sizes, int n_in,
                              void* d_out, int out_size, void* d_ws, size_t ws_size,
                              hipStream_t stream) {
  const float* x  = (const float*)d_in[0];
  const int*   ei = (const int*)d_in[1];
  const float* W1 = (const float*)d_in[2];
  const float* b1 = (const float*)d_in[3];
  const float* W2 = (const float*)d_in[4];
  const float* b2 = (const float*)d_in[5];
  float* out = (float*)d_out;
  const int E = in_sizes[1] / 2;
  const int* esrc = ei;
  const int* edst = ei + E;

  char* w = (char*)d_ws;
  float*          Sf  = (float*)w;                               // [0,64M) f32 dense S
  unsigned short* H1T = (unsigned short*)w;                      // [0,32M)  (after Sf dead)
  unsigned short* W1T = (unsigned short*)(w + (size_t)(32u << 20)); // [32M,64M) (after Sf dead)
  unsigned short* Sbf = (unsigned short*)(w + (size_t)(64u << 20)); // [64M,96M)
  unsigned short* Xbf = (unsigned short*)(w + (size_t)(96u << 20)); // [96M,128M) x_bf then X1_bf
  float* deg  = (float*)(w + (size_t)(128u << 20));
  float* dinv = deg + 4096;
  float* h2   = deg + 8192;
  float* tacc = deg + 12288;

  // graph normalization
  init_deg_kernel<<<16, 256, 0, stream>>>(deg);
  count_deg_kernel<<<(E + 255) / 256, 256, 0, stream>>>(edst, E, deg);
  dinv_kernel<<<16, 256, 0, stream>>>(deg, dinv);

  // dense S (f32, atomics sum duplicate edges), then cast to bf16
  hipMemsetAsync(Sf, 0, (size_t)64 << 20, stream);
  diag_kernel<<<16, 256, 0, stream>>>(dinv, Sf);
  scatter_S_kernel<<<(E + 255) / 256, 256, 0, stream>>>(esrc, edst, E, dinv, Sf);
  cast_kernel<<<8192, 256, 0, stream>>>(Sf, Sbf, NN * NN);

  // operand preparation
  cast_kernel<<<8192, 256, 0, stream>>>(x, Xbf, NN * NN);
  transpose_cast_kernel<<<dim3(128, 128), dim3(32, 8), 0, stream>>>(W1, W1T);

  // layer 1: two MFMA GEMMs
  gemm_bt_kernel<0><<<dim3(32, 32), 256, 0, stream>>>(W1T, Xbf, H1T, nullptr);
  gemm_bt_kernel<1><<<dim3(32, 32), 256, 0, stream>>>(Sbf, H1T, Xbf, b1);

  // layer 2: matvec + scalar aggregation + sigmoid
  matvec_kernel<<<4096, 256, 0, stream>>>(Xbf, W2, h2);
  init_t_kernel<<<16, 256, 0, stream>>>(dinv, h2, b2, tacc);
  scatter_t_kernel<<<(E + 255) / 256, 256, 0, stream>>>(esrc, edst, E, dinv, h2, tacc);
  final_kernel<<<16, 256, 0, stream>>>(tacc, out);
}

// Round 2
// 381.447 us; speedup vs baseline: 1.2995x; 1.2995x over previous
//
#include <hip/hip_runtime.h>

// Discriminator GCN: x2 = sigmoid(GCN2(sigmoid(GCN1(x)))), N=4096, E=262144.
// Layer 1 as two bf16 MFMA GEMMs (dense S); layer 2 = matvec + edge scatter.
// GEMM: 256x256 tile, BK=64, 8 waves, 8-phase counted-vmcnt schedule (T2+T3+T4+T5).

typedef __attribute__((ext_vector_type(8))) short bf16x8;
typedef __attribute__((ext_vector_type(4))) float f32x4;

#define NN 4096
#define NT 64   // K tiles of 64

__device__ __forceinline__ unsigned f2bf(float f) {
  unsigned u = __float_as_uint(f);
  return (u + 0x7FFFu + ((u >> 16) & 1u)) >> 16;   // RNE f32 -> bf16
}

#define GLDS(g, l) __builtin_amdgcn_global_load_lds(                      \
    (const __attribute__((address_space(1))) void*)(g),                   \
    (__attribute__((address_space(3))) void*)(l), 16, 0, 0)

// ---------------- small graph kernels ----------------

__global__ void init_deg_kernel(float* deg) {
  int v = blockIdx.x * 256 + threadIdx.x;
  if (v < NN) deg[v] = 1.0f;
}

__global__ void count_deg_kernel(const int* __restrict__ dst, int E, float* deg) {
  int e = blockIdx.x * 256 + threadIdx.x;
  if (e < E) atomicAdd(&deg[dst[e]], 1.0f);
}

__global__ void dinv_kernel(const float* __restrict__ deg, float* __restrict__ dinv) {
  int v = blockIdx.x * 256 + threadIdx.x;
  if (v < NN) dinv[v] = rsqrtf(deg[v]);
}

__global__ void diag_kernel(const float* __restrict__ dinv, float* __restrict__ S) {
  int v = blockIdx.x * 256 + threadIdx.x;
  if (v < NN) { float d = dinv[v]; S[(size_t)v * NN + v] = d * d; }
}

__global__ void scatter_S_kernel(const int* __restrict__ src, const int* __restrict__ dst,
                                 int E, const float* __restrict__ dinv, float* __restrict__ S) {
  int e = blockIdx.x * 256 + threadIdx.x;
  if (e < E) {
    int s = src[e], d = dst[e];
    atomicAdd(&S[(size_t)d * NN + s], dinv[s] * dinv[d]);
  }
}

// ---------------- casts ----------------

__global__ void cast_kernel(const float* __restrict__ in, unsigned short* __restrict__ out, int n) {
  int i = (blockIdx.x * 256 + threadIdx.x) * 8;
  if (i >= n) return;
  const float4* p = (const float4*)(in + i);
  float4 a = p[0], b = p[1];
  uint4 o;
  o.x = f2bf(a.x) | (f2bf(a.y) << 16);
  o.y = f2bf(a.z) | (f2bf(a.w) << 16);
  o.z = f2bf(b.x) | (f2bf(b.y) << 16);
  o.w = f2bf(b.z) | (f2bf(b.w) << 16);
  *(uint4*)(out + i) = o;
}

__global__ void transpose_cast_kernel(const float* __restrict__ W, unsigned short* __restrict__ WT) {
  __shared__ float tile[32][33];
  int bx = blockIdx.x * 32, by = blockIdx.y * 32;
  int tx = threadIdx.x, ty = threadIdx.y;
#pragma unroll
  for (int i = 0; i < 32; i += 8)
    tile[ty + i][tx] = W[(size_t)(by + ty + i) * NN + bx + tx];
  __syncthreads();
#pragma unroll
  for (int i = 0; i < 32; i += 8)
    WT[(size_t)(bx + ty + i) * NN + by + tx] = (unsigned short)f2bf(tile[tx][ty + i]);
}

// ------------- 256x256 8-phase bf16 GEMM: C[M][N] = A[M][K] * BT[N][K]^T -------------
// LDS per buf: A [256][64] bf16 (32KB, rows 128B, 16B-granule XOR swizzle), B same at +32KB.
// Stage pieces (8KB = 64 rows, one global_load_lds for all 512 threads):
//   phase order B0,B1 | B2,B3 | A0,A2 | A1,A3  (A1/A3 = rows 64..127 of each wave-half,
//   consumed only in phases 3-4 -> stay in flight across the tile boundary).
// vmcnt(4) @P2 guards this tile's late A pieces; vmcnt(2) @P4 guards next tile's 6 early.

template <int EPI>  // 0: bf16 store; 1: +bias, sigmoid, bf16 store
__global__ __launch_bounds__(512, 2) void gemm256_kernel(
    const unsigned short* __restrict__ A, const unsigned short* __restrict__ BT,
    unsigned short* __restrict__ C, const float* __restrict__ bias) {
  __shared__ __align__(16) char smem[131072];
  const int tid = threadIdx.x;
  const int lane = tid & 63, wid = tid >> 6;
  const int wr = wid >> 2, wc = wid & 3;     // 2x4 wave grid; wave owns 128x64 of C

  const int bid = blockIdx.x;
  const int swz = (bid & 7) * 32 + (bid >> 3);   // XCD-aware remap (256 = 8*32)
  const int rowBase = (swz >> 4) * 256;
  const int colBase = (swz & 15) * 256;

  // staging source (per-thread, pre-swizzled column so linear LDS dest = swizzled layout)
  const int srow = tid >> 3;                              // 0..63 within a piece
  const int scolb = ((tid & 7) << 4) ^ ((srow & 7) << 4); // physical->logical col byte
  const unsigned short* pA = A + (size_t)(rowBase + srow) * NN + (scolb >> 1);
  const unsigned short* pB = BT + (size_t)(colBase + srow) * NN + (scolb >> 1);
  char* ldsw = smem + (wid << 10);   // wave-uniform stage dest chunk

  // ds_read swizzled column constants
  const int rl = lane & 15;
  const int c0 = ((lane >> 4) << 4) ^ ((lane & 7) << 4);  // kk=0 physical col byte
  const int c1 = c0 ^ 64;                                  // kk=1
  const int aoff = (wr * 128 + rl) * 128;          // A row byte offset
  const int boff = 32768 + (wc * 64 + rl) * 128;   // B row byte offset

  f32x4 acc[8][4] = {};

  // prologue: stage tile 0 into buf0 (order: 6 early, then A1,A3)
  GLDS(pB + (size_t)0 * 64 * NN, ldsw + 32768 + 0 * 8192);
  GLDS(pB + (size_t)1 * 64 * NN, ldsw + 32768 + 1 * 8192);
  GLDS(pB + (size_t)2 * 64 * NN, ldsw + 32768 + 2 * 8192);
  GLDS(pB + (size_t)3 * 64 * NN, ldsw + 32768 + 3 * 8192);
  GLDS(pA + (size_t)0 * 64 * NN, ldsw + 0 * 8192);
  GLDS(pA + (size_t)2 * 64 * NN, ldsw + 2 * 8192);
  GLDS(pA + (size_t)1 * 64 * NN, ldsw + 1 * 8192);
  GLDS(pA + (size_t)3 * 64 * NN, ldsw + 3 * 8192);
  asm volatile("s_waitcnt vmcnt(2)" ::: "memory");
  __builtin_amdgcn_s_barrier();

  for (int t = 0; t < NT; ++t) {
    const int cur = (t & 1) << 16;
    const char* lb = smem + cur;
    char* stw = ldsw + (cur ^ 65536);
    // t=NT-1 prefetches 64 cols past the end: stays inside adjacent ws regions, never read.
    const unsigned short* sA = pA + (t + 1) * 64;
    const unsigned short* sB = pB + (t + 1) * 64;

    bf16x8 af[4], bk0[4], bk1[4];

    // ---- P1: (mh0, kk0) ----
#pragma unroll
    for (int m = 0; m < 4; ++m) af[m] = *(const bf16x8*)(lb + aoff + m * 2048 + c0);
#pragma unroll
    for (int n = 0; n < 4; ++n) bk0[n] = *(const bf16x8*)(lb + boff + n * 2048 + c0);
    GLDS(sB + (size_t)0 * 64 * NN, stw + 32768 + 0 * 8192);
    GLDS(sB + (size_t)1 * 64 * NN, stw + 32768 + 1 * 8192);
    __builtin_amdgcn_s_barrier();
    asm volatile("s_waitcnt lgkmcnt(0)" ::: "memory");
    __builtin_amdgcn_sched_barrier(0);
    __builtin_amdgcn_s_setprio(1);
#pragma unroll
    for (int m = 0; m < 4; ++m)
#pragma unroll
      for (int n = 0; n < 4; ++n)
        acc[m][n] = __builtin_amdgcn_mfma_f32_16x16x32_bf16(af[m], bk0[n], acc[m][n], 0, 0, 0);
    __builtin_amdgcn_s_setprio(0);
    __builtin_amdgcn_s_barrier();

    // ---- P2: (mh0, kk1) ----
#pragma unroll
    for (int m = 0; m < 4; ++m) af[m] = *(const bf16x8*)(lb + aoff + m * 2048 + c1);
#pragma unroll
    for (int n = 0; n < 4; ++n) bk1[n] = *(const bf16x8*)(lb + boff + n * 2048 + c1);
    GLDS(sB + (size_t)2 * 64 * NN, stw + 32768 + 2 * 8192);
    GLDS(sB + (size_t)3 * 64 * NN, stw + 32768 + 3 * 8192);
    asm volatile("s_waitcnt vmcnt(4)" ::: "memory");   // this tile's A1,A3 have landed
    __builtin_amdgcn_s_barrier();
    asm volatile("s_waitcnt lgkmcnt(0)" ::: "memory");
    __builtin_amdgcn_sched_barrier(0);
    __builtin_amdgcn_s_setprio(1);
#pragma unroll
    for (int m = 0; m < 4; ++m)
#pragma unroll
      for (int n = 0; n < 4; ++n)
        acc[m][n] = __builtin_amdgcn_mfma_f32_16x16x32_bf16(af[m], bk1[n], acc[m][n], 0, 0, 0);
    __builtin_amdgcn_s_setprio(0);
    __builtin_amdgcn_s_barrier();

    // ---- P3: (mh1, kk0) ----
#pragma unroll
    for (int m = 0; m < 4; ++m) af[m] = *(const bf16x8*)(lb + aoff + (4 + m) * 2048 + c0);
    GLDS(sA + (size_t)0 * 64 * NN, stw + 0 * 8192);
    GLDS(sA + (size_t)2 * 64 * NN, stw + 2 * 8192);
    __builtin_amdgcn_s_barrier();
    asm volatile("s_waitcnt lgkmcnt(0)" ::: "memory");
    __builtin_amdgcn_sched_barrier(0);
    __builtin_amdgcn_s_setprio(1);
#pragma unroll
    for (int m = 0; m < 4; ++m)
#pragma unroll
      for (int n = 0; n < 4; ++n)
        acc[4 + m][n] = __builtin_amdgcn_mfma_f32_16x16x32_bf16(af[m], bk0[n], acc[4 + m][n], 0, 0, 0);
    __builtin_amdgcn_s_setprio(0);
    __builtin_amdgcn_s_barrier();

    // ---- P4: (mh1, kk1) ----
#pragma unroll
    for (int m = 0; m < 4; ++m) af[m] = *(const bf16x8*)(lb + aoff + (4 + m) * 2048 + c1);
    GLDS(sA + (size_t)1 * 64 * NN, stw + 1 * 8192);
    GLDS(sA + (size_t)3 * 64 * NN, stw + 3 * 8192);
    asm volatile("s_waitcnt vmcnt(2)" ::: "memory");   // next tile's 6 early pieces landed
    __builtin_amdgcn_s_barrier();
    asm volatile("s_waitcnt lgkmcnt(0)" ::: "memory");
    __builtin_amdgcn_sched_barrier(0);
    __builtin_amdgcn_s_setprio(1);
#pragma unroll
    for (int m = 0; m < 4; ++m)
#pragma unroll
      for (int n = 0; n < 4; ++n)
        acc[4 + m][n] = __builtin_amdgcn_mfma_f32_16x16x32_bf16(af[m], bk1[n], acc[4 + m][n], 0, 0, 0);
    __builtin_amdgcn_s_setprio(0);
    __builtin_amdgcn_s_barrier();
  }

  // ---- epilogue: C write (col = lane&15, row = (lane>>4)*4 + i) ----
  const int orow = rowBase + wr * 128 + (lane >> 4) * 4;
  const int ocol = colBase + wc * 64 + (lane & 15);
#pragma unroll
  for (int n = 0; n < 4; ++n) {
    int ccol = ocol + n * 16;
    float bv = (EPI == 1) ? bias[ccol] : 0.0f;
#pragma unroll
    for (int m = 0; m < 8; ++m) {
#pragma unroll
      for (int i = 0; i < 4; ++i) {
        float x = acc[m][n][i] + bv;
        if (EPI == 1) x = 1.0f / (1.0f + __expf(-x));
        C[(size_t)(orow + m * 16 + i) * NN + ccol] = (unsigned short)f2bf(x);
      }
    }
  }
}

// ---------------- layer 2 ----------------

__global__ void matvec_kernel(const unsigned short* __restrict__ X1,
                              const float* __restrict__ W2, float* __restrict__ h2) {
  int row = blockIdx.x, t = threadIdx.x;
  const unsigned short* xr = X1 + (size_t)row * NN;
  float s = 0.0f;
  for (int j = t * 8; j < NN; j += 2048) {
    uint4 u = *(const uint4*)(xr + j);
    unsigned v[4] = {u.x, u.y, u.z, u.w};
#pragma unroll
    for (int q = 0; q < 4; ++q) {
      float lo = __uint_as_float(v[q] << 16);
      float hi = __uint_as_float(v[q] & 0xFFFF0000u);
      s += lo * W2[j + q * 2] + hi * W2[j + q * 2 + 1];
    }
  }
#pragma unroll
  for (int off = 32; off > 0; off >>= 1) s += __shfl_down(s, off);
  __shared__ float wsum[4];
  if ((t & 63) == 0) wsum[t >> 6] = s;
  __syncthreads();
  if (t == 0) h2[row] = wsum[0] + wsum[1] + wsum[2] + wsum[3];
}

__global__ void init_t_kernel(const float* __restrict__ dinv, const float* __restrict__ h2,
                              const float* __restrict__ b2, float* __restrict__ tacc) {
  int v = blockIdx.x * 256 + threadIdx.x;
  if (v < NN) tacc[v] = dinv[v] * dinv[v] * h2[v] + b2[0];
}

__global__ void scatter_t_kernel(const int* __restrict__ src, const int* __restrict__ dst,
                                 int E, const float* __restrict__ dinv,
                                 const float* __restrict__ h2, float* __restrict__ tacc) {
  int e = blockIdx.x * 256 + threadIdx.x;
  if (e < E) {
    int s = src[e], d = dst[e];
    atomicAdd(&tacc[d], dinv[s] * dinv[d] * h2[s]);
  }
}

__global__ void final_kernel(const float* __restrict__ tacc, float* __restrict__ out) {
  int v = blockIdx.x * 256 + threadIdx.x;
  if (v < NN) out[v] = 1.0f / (1.0f + __expf(-tacc[v]));
}

// ---------------- launch ----------------

extern "C" void kernel_launch(void* const* d_in, const int* in_sizes, int n_in,
                              void* d_out, int out_size, void* d_ws, size_t ws_size,
                              hipStream_t stream) {
  const float* x  = (const float*)d_in[0];
  const int*   ei = (const int*)d_in[1];
  const float* W1 = (const float*)d_in[2];
  const float* b1 = (const float*)d_in[3];
  const float* W2 = (const float*)d_in[4];
  const float* b2 = (const float*)d_in[5];
  float* out = (float*)d_out;
  const int E = in_sizes[1] / 2;
  const int* esrc = ei;
  const int* edst = ei + E;

  char* w = (char*)d_ws;
  float*          Sf  = (float*)w;                                  // [0,64M) f32 dense S
  unsigned short* H1T = (unsigned short*)w;                         // [0,32M)  (after Sf dead)
  unsigned short* W1T = (unsigned short*)(w + (size_t)(32u << 20)); // [32M,64M)
  unsigned short* Sbf = (unsigned short*)(w + (size_t)(64u << 20)); // [64M,96M)
  unsigned short* Xbf = (unsigned short*)(w + (size_t)(96u << 20)); // [96M,128M)
  float* deg  = (float*)(w + (size_t)(128u << 20));
  float* dinv = deg + 4096;
  float* h2   = deg + 8192;
  float* tacc = deg + 12288;

  // graph normalization
  init_deg_kernel<<<16, 256, 0, stream>>>(deg);
  count_deg_kernel<<<(E + 255) / 256, 256, 0, stream>>>(edst, E, deg);
  dinv_kernel<<<16, 256, 0, stream>>>(deg, dinv);

  // dense S (f32, atomics sum duplicate edges), then cast to bf16
  hipMemsetAsync(Sf, 0, (size_t)64 << 20, stream);
  diag_kernel<<<16, 256, 0, stream>>>(dinv, Sf);
  scatter_S_kernel<<<(E + 255) / 256, 256, 0, stream>>>(esrc, edst, E, dinv, Sf);
  cast_kernel<<<8192, 256, 0, stream>>>(Sf, Sbf, NN * NN);

  // operand preparation
  cast_kernel<<<8192, 256, 0, stream>>>(x, Xbf, NN * NN);
  transpose_cast_kernel<<<dim3(128, 128), dim3(32, 8), 0, stream>>>(W1, W1T);

  // layer 1: two MFMA GEMMs (256x256 8-phase)
  gemm256_kernel<0><<<256, 512, 0, stream>>>(W1T, Xbf, H1T, nullptr);
  gemm256_kernel<1><<<256, 512, 0, stream>>>(Sbf, H1T, Xbf, b1);

  // layer 2: matvec + scalar aggregation + sigmoid
  matvec_kernel<<<4096, 256, 0, stream>>>(Xbf, W2, h2);
  init_t_kernel<<<16, 256, 0, stream>>>(dinv, h2, b2, tacc);
  scatter_t_kernel<<<(E + 255) / 256, 256, 0, stream>>>(esrc, edst, E, dinv, h2, tacc);
  final_kernel<<<16, 256, 0, stream>>>(tacc, out);
}

// Round 3
// 367.031 us; speedup vs baseline: 1.3506x; 1.0393x over previous
//
#include <hip/hip_runtime.h>

// Discriminator GCN: x2 = sigmoid(GCN2(sigmoid(GCN1(x)))), N=4096, E=262144.
// Layer 1 as two bf16 MFMA GEMMs (dense S); layer 2 = matvec + edge scatter.
// GEMM: 256x256 tile, BK=64, 8 waves, 8-phase schedule with deep counted-vmcnt
// pipeline (T2 swizzle + T3/T4 counted waits + T5 setprio).

typedef __attribute__((ext_vector_type(8))) short bf16x8;
typedef __attribute__((ext_vector_type(4))) float f32x4;

#define NN 4096
#define NT 64   // K tiles of 64

__device__ __forceinline__ unsigned f2bf(float f) {
  unsigned u = __float_as_uint(f);
  return (u + 0x7FFFu + ((u >> 16) & 1u)) >> 16;   // RNE f32 -> bf16
}

#define GLDS(g, l) __builtin_amdgcn_global_load_lds(                      \
    (const __attribute__((address_space(1))) void*)(g),                   \
    (__attribute__((address_space(3))) void*)(l), 16, 0, 0)

// ---------------- small graph kernels ----------------

__global__ void init_deg_kernel(float* deg) {
  int v = blockIdx.x * 256 + threadIdx.x;
  if (v < NN) deg[v] = 1.0f;
}

__global__ void count_deg_kernel(const int* __restrict__ dst, int E, float* deg) {
  int e = blockIdx.x * 256 + threadIdx.x;
  if (e < E) atomicAdd(&deg[dst[e]], 1.0f);
}

__global__ void dinv_kernel(const float* __restrict__ deg, float* __restrict__ dinv) {
  int v = blockIdx.x * 256 + threadIdx.x;
  if (v < NN) dinv[v] = rsqrtf(deg[v]);
}

__global__ void diag_kernel(const float* __restrict__ dinv, float* __restrict__ S) {
  int v = blockIdx.x * 256 + threadIdx.x;
  if (v < NN) { float d = dinv[v]; S[(size_t)v * NN + v] = d * d; }
}

__global__ void scatter_S_kernel(const int* __restrict__ src, const int* __restrict__ dst,
                                 int E, const float* __restrict__ dinv, float* __restrict__ S) {
  int e = blockIdx.x * 256 + threadIdx.x;
  if (e < E) {
    int s = src[e], d = dst[e];
    atomicAdd(&S[(size_t)d * NN + s], dinv[s] * dinv[d]);
  }
}

// ---------------- casts ----------------

__global__ void cast_kernel(const float* __restrict__ in, unsigned short* __restrict__ out, int n) {
  int i = (blockIdx.x * 256 + threadIdx.x) * 8;
  if (i >= n) return;
  const float4* p = (const float4*)(in + i);
  float4 a = p[0], b = p[1];
  uint4 o;
  o.x = f2bf(a.x) | (f2bf(a.y) << 16);
  o.y = f2bf(a.z) | (f2bf(a.w) << 16);
  o.z = f2bf(b.x) | (f2bf(b.y) << 16);
  o.w = f2bf(b.z) | (f2bf(b.w) << 16);
  *(uint4*)(out + i) = o;
}

__global__ void transpose_cast_kernel(const float* __restrict__ W, unsigned short* __restrict__ WT) {
  __shared__ float tile[32][33];
  int bx = blockIdx.x * 32, by = blockIdx.y * 32;
  int tx = threadIdx.x, ty = threadIdx.y;
#pragma unroll
  for (int i = 0; i < 32; i += 8)
    tile[ty + i][tx] = W[(size_t)(by + ty + i) * NN + bx + tx];
  __syncthreads();
#pragma unroll
  for (int i = 0; i < 32; i += 8)
    WT[(size_t)(bx + ty + i) * NN + by + tx] = (unsigned short)f2bf(tile[tx][ty + i]);
}

// ------------- 256x256 8-phase bf16 GEMM: C[M][N] = A[M][K] * BT[N][K]^T -------------
// LDS per buf (64KB): A [256][64] bf16 rows 128B with 16B-granule XOR swizzle; B at +32KB.
// Pieces (64 rows = 8KB, one GLDS across 512 threads): A0..A3, B0..B3.
// Consumption of tile t: P1/P2 read A-even (A0,A2) + all B; P3/P4 read A-odd + all B.
// Steady-state issue (2 GLDS/phase): P1:B01(t+1) P2:B23(t+1) P3:A13(t+1) P4:A02(t+2,
//   into CUR buf - A-even region dead after P2). Leads: 4/3/4/5 phases.
// Counted waits: end-P2 vmcnt(6) guards A13(t) [issued t-1.P3]; end-P4 vmcnt(4)
//   guards B23(t+1)+older. Max 8 in flight; never drained to 0 in the loop.

template <int EPI>  // 0: bf16 store; 1: +bias, sigmoid, bf16 store
__global__ __launch_bounds__(512, 2) void gemm256_kernel(
    const unsigned short* __restrict__ A, const unsigned short* __restrict__ BT,
    unsigned short* __restrict__ C, const float* __restrict__ bias) {
  __shared__ __align__(16) char smem[131072];
  const int tid = threadIdx.x;
  const int lane = tid & 63, wid = tid >> 6;
  const int wr = wid >> 2, wc = wid & 3;     // 2x4 wave grid; wave owns 128x64 of C

  const int bid = blockIdx.x;
  const int swz = (bid & 7) * 32 + (bid >> 3);   // XCD-aware remap (256 = 8*32)
  const int rowBase = (swz >> 4) * 256;
  const int colBase = (swz & 15) * 256;

  // staging source (per-thread, pre-swizzled column so linear LDS dest = swizzled layout)
  const int srow = tid >> 3;                              // 0..63 within a piece
  const int scolb = ((tid & 7) << 4) ^ ((srow & 7) << 4);
  const unsigned short* pA = A + (size_t)(rowBase + srow) * NN + (scolb >> 1);
  const unsigned short* pB = BT + (size_t)(colBase + srow) * NN + (scolb >> 1);

  // ds_read swizzled column constants
  const int rl = lane & 15;
  const int c0 = ((lane >> 4) << 4) ^ ((lane & 7) << 4);  // kk=0 physical col byte
  const int c1 = c0 ^ 64;                                  // kk=1
  const int aoff = (wr * 128 + rl) * 128;          // A row byte offset
  const int boff = 32768 + (wc * 64 + rl) * 128;   // B row byte offset

  f32x4 acc[8][4] = {};

  // prologue: full tile0 -> buf0, plus tile1's A-even -> buf1
  {
    char* w0 = smem + (wid << 10);
    char* w1 = smem + 65536 + (wid << 10);
    GLDS(pB + (size_t)0 * 64 * NN, w0 + 32768 + 0 * 8192);
    GLDS(pB + (size_t)1 * 64 * NN, w0 + 32768 + 1 * 8192);
    GLDS(pB + (size_t)2 * 64 * NN, w0 + 32768 + 2 * 8192);
    GLDS(pB + (size_t)3 * 64 * NN, w0 + 32768 + 3 * 8192);
    GLDS(pA + (size_t)0 * 64 * NN, w0 + 0 * 8192);
    GLDS(pA + (size_t)2 * 64 * NN, w0 + 2 * 8192);
    GLDS(pA + (size_t)1 * 64 * NN, w0 + 1 * 8192);
    GLDS(pA + (size_t)3 * 64 * NN, w0 + 3 * 8192);
    GLDS(pA + 64 + (size_t)0 * 64 * NN, w1 + 0 * 8192);   // A0(t1)
    GLDS(pA + 64 + (size_t)2 * 64 * NN, w1 + 2 * 8192);   // A2(t1)
    asm volatile("s_waitcnt vmcnt(2)" ::: "memory");
    __builtin_amdgcn_s_barrier();
  }

  for (int t = 0; t < NT; ++t) {
    const int cur = (t & 1) << 16;
    const char* lb = smem + cur;
    char* stN = smem + (cur ^ 65536) + (wid << 10);  // next-tile buf
    char* stC = smem + cur + (wid << 10);            // cur buf (A-even of t+2)
    const unsigned short* s1A = pA + ((t + 1) & 63) * 64;
    const unsigned short* s1B = pB + ((t + 1) & 63) * 64;
    const unsigned short* s2A = pA + ((t + 2) & 63) * 64;

    bf16x8 af[4], bk0[4], bk1[4];

    // ---- P1: (mh0, kk0) ----
#pragma unroll
    for (int m = 0; m < 4; ++m) af[m] = *(const bf16x8*)(lb + aoff + m * 2048 + c0);
#pragma unroll
    for (int n = 0; n < 4; ++n) bk0[n] = *(const bf16x8*)(lb + boff + n * 2048 + c0);
    GLDS(s1B + (size_t)0 * 64 * NN, stN + 32768 + 0 * 8192);
    GLDS(s1B + (size_t)1 * 64 * NN, stN + 32768 + 1 * 8192);
    __builtin_amdgcn_s_barrier();
    asm volatile("s_waitcnt lgkmcnt(0)" ::: "memory");
    __builtin_amdgcn_sched_barrier(0);
    __builtin_amdgcn_s_setprio(1);
#pragma unroll
    for (int m = 0; m < 4; ++m)
#pragma unroll
      for (int n = 0; n < 4; ++n)
        acc[m][n] = __builtin_amdgcn_mfma_f32_16x16x32_bf16(af[m], bk0[n], acc[m][n], 0, 0, 0);
    __builtin_amdgcn_s_setprio(0);
    __builtin_amdgcn_s_barrier();

    // ---- P2: (mh0, kk1) ----
#pragma unroll
    for (int m = 0; m < 4; ++m) af[m] = *(const bf16x8*)(lb + aoff + m * 2048 + c1);
#pragma unroll
    for (int n = 0; n < 4; ++n) bk1[n] = *(const bf16x8*)(lb + boff + n * 2048 + c1);
    GLDS(s1B + (size_t)2 * 64 * NN, stN + 32768 + 2 * 8192);
    GLDS(s1B + (size_t)3 * 64 * NN, stN + 32768 + 3 * 8192);
    __builtin_amdgcn_s_barrier();
    asm volatile("s_waitcnt lgkmcnt(0)" ::: "memory");
    __builtin_amdgcn_sched_barrier(0);
    __builtin_amdgcn_s_setprio(1);
#pragma unroll
    for (int m = 0; m < 4; ++m)
#pragma unroll
      for (int n = 0; n < 4; ++n)
        acc[m][n] = __builtin_amdgcn_mfma_f32_16x16x32_bf16(af[m], bk1[n], acc[m][n], 0, 0, 0);
    __builtin_amdgcn_s_setprio(0);
    asm volatile("s_waitcnt vmcnt(6)" ::: "memory");   // A13(t) landed (issued t-1.P3)
    __builtin_amdgcn_s_barrier();

    // ---- P3: (mh1, kk0) ----
#pragma unroll
    for (int m = 0; m < 4; ++m) af[m] = *(const bf16x8*)(lb + aoff + (4 + m) * 2048 + c0);
    GLDS(s1A + (size_t)1 * 64 * NN, stN + 1 * 8192);
    GLDS(s1A + (size_t)3 * 64 * NN, stN + 3 * 8192);
    __builtin_amdgcn_s_barrier();
    asm volatile("s_waitcnt lgkmcnt(0)" ::: "memory");
    __builtin_amdgcn_sched_barrier(0);
    __builtin_amdgcn_s_setprio(1);
#pragma unroll
    for (int m = 0; m < 4; ++m)
#pragma unroll
      for (int n = 0; n < 4; ++n)
        acc[4 + m][n] = __builtin_amdgcn_mfma_f32_16x16x32_bf16(af[m], bk0[n], acc[4 + m][n], 0, 0, 0);
    __builtin_amdgcn_s_setprio(0);
    __builtin_amdgcn_s_barrier();

    // ---- P4: (mh1, kk1) ----
#pragma unroll
    for (int m = 0; m < 4; ++m) af[m] = *(const bf16x8*)(lb + aoff + (4 + m) * 2048 + c1);
    GLDS(s2A + (size_t)0 * 64 * NN, stC + 0 * 8192);   // A0(t+2) into cur buf (dead region)
    GLDS(s2A + (size_t)2 * 64 * NN, stC + 2 * 8192);   // A2(t+2)
    __builtin_amdgcn_s_barrier();
    asm volatile("s_waitcnt lgkmcnt(0)" ::: "memory");
    __builtin_amdgcn_sched_barrier(0);
    __builtin_amdgcn_s_setprio(1);
#pragma unroll
    for (int m = 0; m < 4; ++m)
#pragma unroll
      for (int n = 0; n < 4; ++n)
        acc[4 + m][n] = __builtin_amdgcn_mfma_f32_16x16x32_bf16(af[m], bk1[n], acc[4 + m][n], 0, 0, 0);
    __builtin_amdgcn_s_setprio(0);
    asm volatile("s_waitcnt vmcnt(4)" ::: "memory");   // B(t+1)+A02(t+1) landed
    __builtin_amdgcn_s_barrier();
  }

  // ---- epilogue: C write (col = lane&15, row = (lane>>4)*4 + i) ----
  const int orow = rowBase + wr * 128 + (lane >> 4) * 4;
  const int ocol = colBase + wc * 64 + (lane & 15);
#pragma unroll
  for (int n = 0; n < 4; ++n) {
    int ccol = ocol + n * 16;
    float bv = (EPI == 1) ? bias[ccol] : 0.0f;
#pragma unroll
    for (int m = 0; m < 8; ++m) {
#pragma unroll
      for (int i = 0; i < 4; ++i) {
        float x = acc[m][n][i] + bv;
        if (EPI == 1) x = 1.0f / (1.0f + __expf(-x));
        C[(size_t)(orow + m * 16 + i) * NN + ccol] = (unsigned short)f2bf(x);
      }
    }
  }
}

// ---------------- layer 2 ----------------

__global__ void matvec_kernel(const unsigned short* __restrict__ X1,
                              const float* __restrict__ W2, float* __restrict__ h2) {
  int row = blockIdx.x, t = threadIdx.x;
  const unsigned short* xr = X1 + (size_t)row * NN;
  float s = 0.0f;
  for (int j = t * 8; j < NN; j += 2048) {
    uint4 u = *(const uint4*)(xr + j);
    unsigned v[4] = {u.x, u.y, u.z, u.w};
#pragma unroll
    for (int q = 0; q < 4; ++q) {
      float lo = __uint_as_float(v[q] << 16);
      float hi = __uint_as_float(v[q] & 0xFFFF0000u);
      s += lo * W2[j + q * 2] + hi * W2[j + q * 2 + 1];
    }
  }
#pragma unroll
  for (int off = 32; off > 0; off >>= 1) s += __shfl_down(s, off);
  __shared__ float wsum[4];
  if ((t & 63) == 0) wsum[t >> 6] = s;
  __syncthreads();
  if (t == 0) h2[row] = wsum[0] + wsum[1] + wsum[2] + wsum[3];
}

__global__ void init_t_kernel(const float* __restrict__ dinv, const float* __restrict__ h2,
                              const float* __restrict__ b2, float* __restrict__ tacc) {
  int v = blockIdx.x * 256 + threadIdx.x;
  if (v < NN) tacc[v] = dinv[v] * dinv[v] * h2[v] + b2[0];
}

__global__ void scatter_t_kernel(const int* __restrict__ src, const int* __restrict__ dst,
                                 int E, const float* __restrict__ dinv,
                                 const float* __restrict__ h2, float* __restrict__ tacc) {
  int e = blockIdx.x * 256 + threadIdx.x;
  if (e < E) {
    int s = src[e], d = dst[e];
    atomicAdd(&tacc[d], dinv[s] * dinv[d] * h2[s]);
  }
}

__global__ void final_kernel(const float* __restrict__ tacc, float* __restrict__ out) {
  int v = blockIdx.x * 256 + threadIdx.x;
  if (v < NN) out[v] = 1.0f / (1.0f + __expf(-tacc[v]));
}

// ---------------- launch ----------------

extern "C" void kernel_launch(void* const* d_in, const int* in_sizes, int n_in,
                              void* d_out, int out_size, void* d_ws, size_t ws_size,
                              hipStream_t stream) {
  const float* x  = (const float*)d_in[0];
  const int*   ei = (const int*)d_in[1];
  const float* W1 = (const float*)d_in[2];
  const float* b1 = (const float*)d_in[3];
  const float* W2 = (const float*)d_in[4];
  const float* b2 = (const float*)d_in[5];
  float* out = (float*)d_out;
  const int E = in_sizes[1] / 2;
  const int* esrc = ei;
  const int* edst = ei + E;

  char* w = (char*)d_ws;
  float*          Sf  = (float*)w;                                  // [0,64M) f32 dense S
  unsigned short* H1T = (unsigned short*)w;                         // [0,32M)  (after Sf dead)
  unsigned short* W1T = (unsigned short*)(w + (size_t)(32u << 20)); // [32M,64M)
  unsigned short* Sbf = (unsigned short*)(w + (size_t)(64u << 20)); // [64M,96M)
  unsigned short* Xbf = (unsigned short*)(w + (size_t)(96u << 20)); // [96M,128M)
  float* deg  = (float*)(w + (size_t)(128u << 20));
  float* dinv = deg + 4096;
  float* h2   = deg + 8192;
  float* tacc = deg + 12288;

  // graph normalization
  init_deg_kernel<<<16, 256, 0, stream>>>(deg);
  count_deg_kernel<<<(E + 255) / 256, 256, 0, stream>>>(edst, E, deg);
  dinv_kernel<<<16, 256, 0, stream>>>(deg, dinv);

  // dense S (f32, atomics sum duplicate edges), then cast to bf16
  hipMemsetAsync(Sf, 0, (size_t)64 << 20, stream);
  diag_kernel<<<16, 256, 0, stream>>>(dinv, Sf);
  scatter_S_kernel<<<(E + 255) / 256, 256, 0, stream>>>(esrc, edst, E, dinv, Sf);
  cast_kernel<<<8192, 256, 0, stream>>>(Sf, Sbf, NN * NN);

  // operand preparation
  cast_kernel<<<8192, 256, 0, stream>>>(x, Xbf, NN * NN);
  transpose_cast_kernel<<<dim3(128, 128), dim3(32, 8), 0, stream>>>(W1, W1T);

  // layer 1: two MFMA GEMMs (256x256 8-phase, deep pipeline)
  gemm256_kernel<0><<<256, 512, 0, stream>>>(W1T, Xbf, H1T, nullptr);
  gemm256_kernel<1><<<256, 512, 0, stream>>>(Sbf, H1T, Xbf, b1);

  // layer 2: matvec + scalar aggregation + sigmoid
  matvec_kernel<<<4096, 256, 0, stream>>>(Xbf, W2, h2);
  init_t_kernel<<<16, 256, 0, stream>>>(dinv, h2, b2, tacc);
  scatter_t_kernel<<<(E + 255) / 256, 256, 0, stream>>>(esrc, edst, E, dinv, h2, tacc);
  final_kernel<<<16, 256, 0, stream>>>(tacc, out);
}

// Round 4
// 353.602 us; speedup vs baseline: 1.4019x; 1.0380x over previous
//
#include <hip/hip_runtime.h>

// Discriminator GCN: x2 = sigmoid(GCN2(sigmoid(GCN1(x)))), N=4096, E=262144.
// Layer 1 as two bf16 MFMA GEMMs (dense S); layer 2 = matvec + edge scatter.
// GEMM: 256x256 tile, BK=64, 8 waves. Register-level software pipeline:
// phase p issues phase p+1's ds_reads, MFMA consumes regs loaded in p-1;
// compiler emits per-dependency lgkmcnt waits -> LDS pipe overlaps MFMA pipe.
// ONE barrier per K-tile (buffer reuse only) + counted vmcnt staging guards.

typedef __attribute__((ext_vector_type(8))) short bf16x8;
typedef __attribute__((ext_vector_type(4))) float f32x4;

#define NN 4096
#define NT 64   // K tiles of 64

__device__ __forceinline__ unsigned f2bf(float f) {
  unsigned u = __float_as_uint(f);
  return (u + 0x7FFFu + ((u >> 16) & 1u)) >> 16;   // RNE f32 -> bf16
}

#define GLDS(g, l) __builtin_amdgcn_global_load_lds(                      \
    (const __attribute__((address_space(1))) void*)(g),                   \
    (__attribute__((address_space(3))) void*)(l), 16, 0, 0)

// ---------------- small graph kernels ----------------

__global__ void init_deg_kernel(float* deg) {
  int v = blockIdx.x * 256 + threadIdx.x;
  if (v < NN) deg[v] = 1.0f;
}

__global__ void count_deg_kernel(const int* __restrict__ dst, int E, float* deg) {
  int e = blockIdx.x * 256 + threadIdx.x;
  if (e < E) atomicAdd(&deg[dst[e]], 1.0f);
}

__global__ void dinv_kernel(const float* __restrict__ deg, float* __restrict__ dinv) {
  int v = blockIdx.x * 256 + threadIdx.x;
  if (v < NN) dinv[v] = rsqrtf(deg[v]);
}

__global__ void diag_kernel(const float* __restrict__ dinv, float* __restrict__ S) {
  int v = blockIdx.x * 256 + threadIdx.x;
  if (v < NN) { float d = dinv[v]; S[(size_t)v * NN + v] = d * d; }
}

__global__ void scatter_S_kernel(const int* __restrict__ src, const int* __restrict__ dst,
                                 int E, const float* __restrict__ dinv, float* __restrict__ S) {
  int e = blockIdx.x * 256 + threadIdx.x;
  if (e < E) {
    int s = src[e], d = dst[e];
    atomicAdd(&S[(size_t)d * NN + s], dinv[s] * dinv[d]);
  }
}

// ---------------- casts ----------------

__global__ void cast_kernel(const float* __restrict__ in, unsigned short* __restrict__ out, int n) {
  int i = (blockIdx.x * 256 + threadIdx.x) * 8;
  if (i >= n) return;
  const float4* p = (const float4*)(in + i);
  float4 a = p[0], b = p[1];
  uint4 o;
  o.x = f2bf(a.x) | (f2bf(a.y) << 16);
  o.y = f2bf(a.z) | (f2bf(a.w) << 16);
  o.z = f2bf(b.x) | (f2bf(b.y) << 16);
  o.w = f2bf(b.z) | (f2bf(b.w) << 16);
  *(uint4*)(out + i) = o;
}

__global__ void transpose_cast_kernel(const float* __restrict__ W, unsigned short* __restrict__ WT) {
  __shared__ float tile[32][33];
  int bx = blockIdx.x * 32, by = blockIdx.y * 32;
  int tx = threadIdx.x, ty = threadIdx.y;
#pragma unroll
  for (int i = 0; i < 32; i += 8)
    tile[ty + i][tx] = W[(size_t)(by + ty + i) * NN + bx + tx];
  __syncthreads();
#pragma unroll
  for (int i = 0; i < 32; i += 8)
    WT[(size_t)(bx + ty + i) * NN + by + tx] = (unsigned short)f2bf(tile[tx][ty + i]);
}

// ------------- 256x256 bf16 GEMM: C[M][N] = A[M][K] * BT[N][K]^T -------------
// LDS per buf (64KB): A [256][64] bf16 rows 128B with 16B-granule XOR swizzle; B at +32KB.
// Pieces (64 rows = 8KB): A0..A3, B0..B3. Phase (mh,kk) consumption per wave:
//   P1(mh0,kk0) P2(mh0,kk1) P3(mh1,kk0) P4(mh1,kk1); bk0/bk1 live whole tile.
// Staging of t+1 (into other buf): P1: B0,B1,B2  P2: B3,A0,A2  P3: A1,A3  P4: none.
// Guards: end-P1 vmcnt(3) [A-odd(t) landed before P2 issues mh1 reads];
//         end-P4 lgkmcnt(0) + vmcnt(2) + barrier [all buf reads done; 6 early of t+1 in].
// Fragment reads issued one phase ahead; NO explicit lgkm before MFMA (compiler
// emits counted per-dependency waits -> ds_read overlaps MFMA).

template <int EPI>  // 0: bf16 store; 1: +bias, sigmoid, bf16 store
__global__ __launch_bounds__(512, 2) void gemm256_kernel(
    const unsigned short* __restrict__ A, const unsigned short* __restrict__ BT,
    unsigned short* __restrict__ C, const float* __restrict__ bias) {
  __shared__ __align__(16) char smem[131072];
  const int tid = threadIdx.x;
  const int lane = tid & 63, wid = tid >> 6;
  const int wr = wid >> 2, wc = wid & 3;     // 2x4 wave grid; wave owns 128x64 of C

  const int bid = blockIdx.x;
  const int swz = (bid & 7) * 32 + (bid >> 3);   // XCD-aware remap (256 = 8*32)
  const int rowBase = (swz >> 4) * 256;
  const int colBase = (swz & 15) * 256;

  // staging source (per-thread, pre-swizzled column so linear LDS dest = swizzled layout)
  const int srow = tid >> 3;                              // 0..63 within a piece
  const int scolb = ((tid & 7) << 4) ^ ((srow & 7) << 4);
  const unsigned short* pA = A + (size_t)(rowBase + srow) * NN + (scolb >> 1);
  const unsigned short* pB = BT + (size_t)(colBase + srow) * NN + (scolb >> 1);

  // ds_read swizzled column constants
  const int rl = lane & 15;
  const int c0 = ((lane >> 4) << 4) ^ ((lane & 7) << 4);  // kk=0 physical col byte
  const int c1 = c0 ^ 64;                                  // kk=1
  const int aoff = (wr * 128 + rl) * 128;          // A row byte base (mh0,m=0)
  const int boff = 32768 + (wc * 64 + rl) * 128;   // B row byte base

  f32x4 acc[8][4] = {};
  bf16x8 bk0[4], bk1[4], afA[4], afB[4];

  // prologue: stage tile0 -> buf0 (A-odd last), then preload P1 frags
  {
    char* w0 = smem + (wid << 10);
    GLDS(pB + (size_t)0 * 64 * NN, w0 + 32768 + 0 * 8192);
    GLDS(pB + (size_t)1 * 64 * NN, w0 + 32768 + 1 * 8192);
    GLDS(pB + (size_t)2 * 64 * NN, w0 + 32768 + 2 * 8192);
    GLDS(pB + (size_t)3 * 64 * NN, w0 + 32768 + 3 * 8192);
    GLDS(pA + (size_t)0 * 64 * NN, w0 + 0 * 8192);
    GLDS(pA + (size_t)2 * 64 * NN, w0 + 2 * 8192);
    GLDS(pA + (size_t)1 * 64 * NN, w0 + 1 * 8192);
    GLDS(pA + (size_t)3 * 64 * NN, w0 + 3 * 8192);
    asm volatile("s_waitcnt vmcnt(2)" ::: "memory");
    __builtin_amdgcn_s_barrier();
#pragma unroll
    for (int m = 0; m < 4; ++m) afA[m] = *(const bf16x8*)(smem + aoff + m * 2048 + c0);
#pragma unroll
    for (int n = 0; n < 4; ++n) bk0[n] = *(const bf16x8*)(smem + boff + n * 2048 + c0);
  }

#pragma unroll 2
  for (int t = 0; t < NT; ++t) {
    const char* lb = smem + ((t & 1) << 16);
    char* st = smem + (((t & 1) ^ 1) << 16) + (wid << 10);
    const unsigned short* s1A = pA + ((t + 1) & 63) * 64;
    const unsigned short* s1B = pB + ((t + 1) & 63) * 64;

    // ---- P1: MFMA(mh0,kk0) on afA,bk0; prefetch P2 frags; stage B012(t+1) ----
    GLDS(s1B + (size_t)0 * 64 * NN, st + 32768 + 0 * 8192);
    GLDS(s1B + (size_t)1 * 64 * NN, st + 32768 + 1 * 8192);
    GLDS(s1B + (size_t)2 * 64 * NN, st + 32768 + 2 * 8192);
#pragma unroll
    for (int m = 0; m < 4; ++m) afB[m] = *(const bf16x8*)(lb + aoff + m * 2048 + c1);
#pragma unroll
    for (int n = 0; n < 4; ++n) bk1[n] = *(const bf16x8*)(lb + boff + n * 2048 + c1);
    __builtin_amdgcn_s_setprio(1);
#pragma unroll
    for (int m = 0; m < 4; ++m)
#pragma unroll
      for (int n = 0; n < 4; ++n)
        acc[m][n] = __builtin_amdgcn_mfma_f32_16x16x32_bf16(afA[m], bk0[n], acc[m][n], 0, 0, 0);
    __builtin_amdgcn_s_setprio(0);
    asm volatile("s_waitcnt vmcnt(3)" ::: "memory");   // A-odd(t) landed
    __builtin_amdgcn_sched_barrier(0);

    // ---- P2: MFMA(mh0,kk1) on afB,bk1; prefetch P3 frags; stage B3,A0,A2(t+1) ----
    GLDS(s1B + (size_t)3 * 64 * NN, st + 32768 + 3 * 8192);
    GLDS(s1A + (size_t)0 * 64 * NN, st + 0 * 8192);
    GLDS(s1A + (size_t)2 * 64 * NN, st + 2 * 8192);
#pragma unroll
    for (int m = 0; m < 4; ++m) afA[m] = *(const bf16x8*)(lb + aoff + (4 + m) * 2048 + c0);
    __builtin_amdgcn_s_setprio(1);
#pragma unroll
    for (int m = 0; m < 4; ++m)
#pragma unroll
      for (int n = 0; n < 4; ++n)
        acc[m][n] = __builtin_amdgcn_mfma_f32_16x16x32_bf16(afB[m], bk1[n], acc[m][n], 0, 0, 0);
    __builtin_amdgcn_s_setprio(0);
    __builtin_amdgcn_sched_barrier(0);

    // ---- P3: MFMA(mh1,kk0) on afA,bk0; prefetch P4 frags; stage A1,A3(t+1) ----
    GLDS(s1A + (size_t)1 * 64 * NN, st + 1 * 8192);
    GLDS(s1A + (size_t)3 * 64 * NN, st + 3 * 8192);
#pragma unroll
    for (int m = 0; m < 4; ++m) afB[m] = *(const bf16x8*)(lb + aoff + (4 + m) * 2048 + c1);
    __builtin_amdgcn_s_setprio(1);
#pragma unroll
    for (int m = 0; m < 4; ++m)
#pragma unroll
      for (int n = 0; n < 4; ++n)
        acc[4 + m][n] = __builtin_amdgcn_mfma_f32_16x16x32_bf16(afA[m], bk0[n], acc[4 + m][n], 0, 0, 0);
    __builtin_amdgcn_s_setprio(0);
    __builtin_amdgcn_sched_barrier(0);

    // ---- P4: MFMA(mh1,kk1) on afB,bk1; tile-end sync; preload next P1 frags ----
    __builtin_amdgcn_s_setprio(1);
#pragma unroll
    for (int m = 0; m < 4; ++m)
#pragma unroll
      for (int n = 0; n < 4; ++n)
        acc[4 + m][n] = __builtin_amdgcn_mfma_f32_16x16x32_bf16(afB[m], bk1[n], acc[4 + m][n], 0, 0, 0);
    __builtin_amdgcn_s_setprio(0);
    asm volatile("s_waitcnt lgkmcnt(0)" ::: "memory");  // all reads of lb retired (per wave)
    asm volatile("s_waitcnt vmcnt(2)" ::: "memory");    // 6 early pieces of t+1 landed
    __builtin_amdgcn_s_barrier();                       // buf reuse fence (1 per tile)
    {
      const char* nb = smem + (((t + 1) & 1) << 16);
#pragma unroll
      for (int m = 0; m < 4; ++m) afA[m] = *(const bf16x8*)(nb + aoff + m * 2048 + c0);
#pragma unroll
      for (int n = 0; n < 4; ++n) bk0[n] = *(const bf16x8*)(nb + boff + n * 2048 + c0);
    }
    __builtin_amdgcn_sched_barrier(0);
  }

  // ---- epilogue: C write (col = lane&15, row = (lane>>4)*4 + i) ----
  const int orow = rowBase + wr * 128 + (lane >> 4) * 4;
  const int ocol = colBase + wc * 64 + (lane & 15);
#pragma unroll
  for (int n = 0; n < 4; ++n) {
    int ccol = ocol + n * 16;
    float bv = (EPI == 1) ? bias[ccol] : 0.0f;
#pragma unroll
    for (int m = 0; m < 8; ++m) {
#pragma unroll
      for (int i = 0; i < 4; ++i) {
        float x = acc[m][n][i] + bv;
        if (EPI == 1) x = 1.0f / (1.0f + __expf(-x));
        C[(size_t)(orow + m * 16 + i) * NN + ccol] = (unsigned short)f2bf(x);
      }
    }
  }
}

// ---------------- layer 2 ----------------

__global__ void matvec_kernel(const unsigned short* __restrict__ X1,
                              const float* __restrict__ W2, float* __restrict__ h2) {
  int row = blockIdx.x, t = threadIdx.x;
  const unsigned short* xr = X1 + (size_t)row * NN;
  float s = 0.0f;
  for (int j = t * 8; j < NN; j += 2048) {
    uint4 u = *(const uint4*)(xr + j);
    unsigned v[4] = {u.x, u.y, u.z, u.w};
#pragma unroll
    for (int q = 0; q < 4; ++q) {
      float lo = __uint_as_float(v[q] << 16);
      float hi = __uint_as_float(v[q] & 0xFFFF0000u);
      s += lo * W2[j + q * 2] + hi * W2[j + q * 2 + 1];
    }
  }
#pragma unroll
  for (int off = 32; off > 0; off >>= 1) s += __shfl_down(s, off);
  __shared__ float wsum[4];
  if ((t & 63) == 0) wsum[t >> 6] = s;
  __syncthreads();
  if (t == 0) h2[row] = wsum[0] + wsum[1] + wsum[2] + wsum[3];
}

__global__ void init_t_kernel(const float* __restrict__ dinv, const float* __restrict__ h2,
                              const float* __restrict__ b2, float* __restrict__ tacc) {
  int v = blockIdx.x * 256 + threadIdx.x;
  if (v < NN) tacc[v] = dinv[v] * dinv[v] * h2[v] + b2[0];
}

__global__ void scatter_t_kernel(const int* __restrict__ src, const int* __restrict__ dst,
                                 int E, const float* __restrict__ dinv,
                                 const float* __restrict__ h2, float* __restrict__ tacc) {
  int e = blockIdx.x * 256 + threadIdx.x;
  if (e < E) {
    int s = src[e], d = dst[e];
    atomicAdd(&tacc[d], dinv[s] * dinv[d] * h2[s]);
  }
}

__global__ void final_kernel(const float* __restrict__ tacc, float* __restrict__ out) {
  int v = blockIdx.x * 256 + threadIdx.x;
  if (v < NN) out[v] = 1.0f / (1.0f + __expf(-tacc[v]));
}

// ---------------- launch ----------------

extern "C" void kernel_launch(void* const* d_in, const int* in_sizes, int n_in,
                              void* d_out, int out_size, void* d_ws, size_t ws_size,
                              hipStream_t stream) {
  const float* x  = (const float*)d_in[0];
  const int*   ei = (const int*)d_in[1];
  const float* W1 = (const float*)d_in[2];
  const float* b1 = (const float*)d_in[3];
  const float* W2 = (const float*)d_in[4];
  const float* b2 = (const float*)d_in[5];
  float* out = (float*)d_out;
  const int E = in_sizes[1] / 2;
  const int* esrc = ei;
  const int* edst = ei + E;

  char* w = (char*)d_ws;
  float*          Sf  = (float*)w;                                  // [0,64M) f32 dense S
  unsigned short* H1T = (unsigned short*)w;                         // [0,32M)  (after Sf dead)
  unsigned short* W1T = (unsigned short*)(w + (size_t)(32u << 20)); // [32M,64M)
  unsigned short* Sbf = (unsigned short*)(w + (size_t)(64u << 20)); // [64M,96M)
  unsigned short* Xbf = (unsigned short*)(w + (size_t)(96u << 20)); // [96M,128M)
  float* deg  = (float*)(w + (size_t)(128u << 20));
  float* dinv = deg + 4096;
  float* h2   = deg + 8192;
  float* tacc = deg + 12288;

  // graph normalization
  init_deg_kernel<<<16, 256, 0, stream>>>(deg);
  count_deg_kernel<<<(E + 255) / 256, 256, 0, stream>>>(edst, E, deg);
  dinv_kernel<<<16, 256, 0, stream>>>(deg, dinv);

  // dense S (f32, atomics sum duplicate edges), then cast to bf16
  hipMemsetAsync(Sf, 0, (size_t)64 << 20, stream);
  diag_kernel<<<16, 256, 0, stream>>>(dinv, Sf);
  scatter_S_kernel<<<(E + 255) / 256, 256, 0, stream>>>(esrc, edst, E, dinv, Sf);
  cast_kernel<<<8192, 256, 0, stream>>>(Sf, Sbf, NN * NN);

  // operand preparation
  cast_kernel<<<8192, 256, 0, stream>>>(x, Xbf, NN * NN);
  transpose_cast_kernel<<<dim3(128, 128), dim3(32, 8), 0, stream>>>(W1, W1T);

  // layer 1: two MFMA GEMMs (256x256 register-pipelined)
  gemm256_kernel<0><<<256, 512, 0, stream>>>(W1T, Xbf, H1T, nullptr);
  gemm256_kernel<1><<<256, 512, 0, stream>>>(Sbf, H1T, Xbf, b1);

  // layer 2: matvec + scalar aggregation + sigmoid
  matvec_kernel<<<4096, 256, 0, stream>>>(Xbf, W2, h2);
  init_t_kernel<<<16, 256, 0, stream>>>(dinv, h2, b2, tacc);
  scatter_t_kernel<<<(E + 255) / 256, 256, 0, stream>>>(esrc, edst, E, dinv, h2, tacc);
  final_kernel<<<16, 256, 0, stream>>>(tacc, out);
}

// Round 5
// 345.263 us; speedup vs baseline: 1.4357x; 1.0242x over previous
//
#include <hip/hip_runtime.h>

// Discriminator GCN: x2 = sigmoid(GCN2(sigmoid(GCN1(x)))), N=4096, E=262144.
// Layer 1 as two bf16 MFMA GEMMs (dense S). GEMM2 fuses bias+sigmoid+W2-matvec
// into its epilogue (X1 never materialized). Layer 2 remainder = edge scatter.
// GEMM: 256x256 tile, BK=64, 8 waves, register software pipeline with the
// buffer barrier at P3-end and next-tile fragment preload under P4's MFMAs.

typedef __attribute__((ext_vector_type(8))) short bf16x8;
typedef __attribute__((ext_vector_type(4))) float f32x4;

#define NN 4096
#define NT 64   // K tiles of 64

__device__ __forceinline__ unsigned f2bf(float f) {
  unsigned u = __float_as_uint(f);
  return (u + 0x7FFFu + ((u >> 16) & 1u)) >> 16;   // RNE f32 -> bf16
}

#define GLDS(g, l) __builtin_amdgcn_global_load_lds(                      \
    (const __attribute__((address_space(1))) void*)(g),                   \
    (__attribute__((address_space(3))) void*)(l), 16, 0, 0)

// ---------------- small graph kernels ----------------

__global__ void init_deg_kernel(float* deg) {
  int v = blockIdx.x * 256 + threadIdx.x;
  if (v < NN) deg[v] = 1.0f;
}

__global__ void count_deg_kernel(const int* __restrict__ dst, int E, float* deg) {
  int e = blockIdx.x * 256 + threadIdx.x;
  if (e < E) atomicAdd(&deg[dst[e]], 1.0f);
}

__global__ void dinv_kernel(const float* __restrict__ deg, float* __restrict__ dinv) {
  int v = blockIdx.x * 256 + threadIdx.x;
  if (v < NN) dinv[v] = rsqrtf(deg[v]);
}

__global__ void diag_kernel(const float* __restrict__ dinv, float* __restrict__ S) {
  int v = blockIdx.x * 256 + threadIdx.x;
  if (v < NN) { float d = dinv[v]; S[(size_t)v * NN + v] = d * d; }
}

__global__ void scatter_S_kernel(const int* __restrict__ src, const int* __restrict__ dst,
                                 int E, const float* __restrict__ dinv, float* __restrict__ S) {
  int e = blockIdx.x * 256 + threadIdx.x;
  if (e < E) {
    int s = src[e], d = dst[e];
    atomicAdd(&S[(size_t)d * NN + s], dinv[s] * dinv[d]);
  }
}

// ---------------- casts ----------------

__global__ void cast_kernel(const float* __restrict__ in, unsigned short* __restrict__ out, int n) {
  int i = (blockIdx.x * 256 + threadIdx.x) * 8;
  if (i >= n) return;
  const float4* p = (const float4*)(in + i);
  float4 a = p[0], b = p[1];
  uint4 o;
  o.x = f2bf(a.x) | (f2bf(a.y) << 16);
  o.y = f2bf(a.z) | (f2bf(a.w) << 16);
  o.z = f2bf(b.x) | (f2bf(b.y) << 16);
  o.w = f2bf(b.z) | (f2bf(b.w) << 16);
  *(uint4*)(out + i) = o;
}

__global__ void transpose_cast_kernel(const float* __restrict__ W, unsigned short* __restrict__ WT) {
  __shared__ float tile[32][33];
  int bx = blockIdx.x * 32, by = blockIdx.y * 32;
  int tx = threadIdx.x, ty = threadIdx.y;
#pragma unroll
  for (int i = 0; i < 32; i += 8)
    tile[ty + i][tx] = W[(size_t)(by + ty + i) * NN + bx + tx];
  __syncthreads();
#pragma unroll
  for (int i = 0; i < 32; i += 8)
    WT[(size_t)(bx + ty + i) * NN + by + tx] = (unsigned short)f2bf(tile[tx][ty + i]);
}

// ------------- 256x256 bf16 GEMM: C[M][N] = A[M][K] * BT[N][K]^T -------------
// LDS per buf (64KB): A [256][64] bf16 rows 128B with 16B-granule XOR swizzle; B at +32KB.
// Pieces (64 rows = 8KB): A0..A3, B0..B3. Phases P1(mh0,k0) P2(mh0,k1) P3(mh1,k0) P4(mh1,k1).
// Staging of t+1: P1: B0,B1,B2  P2: B3,A0,A2  P3: A1,A3.
// Guards: P1-end vmcnt(3) [A-odd(t) landed before P2 prefetches mh1 rows];
//         P3-end lgkmcnt(0)+vmcnt(2)+barrier [no lb reads remain; 6 early of t+1 in].
// P4 preloads next tile's P1 frags BEFORE its MFMAs -> reads land under the burst.
// EPI=0: bf16 C store. EPI=1: sigmoid(acc+b1) dotted with W2, shfl-reduced,
//        atomicAdd into h2 (X1 never written).

template <int EPI>
__global__ __launch_bounds__(512, 2) void gemm256_kernel(
    const unsigned short* __restrict__ A, const unsigned short* __restrict__ BT,
    unsigned short* __restrict__ C, const float* __restrict__ bias,
    const float* __restrict__ W2, float* __restrict__ h2) {
  __shared__ __align__(16) char smem[131072];
  const int tid = threadIdx.x;
  const int lane = tid & 63, wid = tid >> 6;
  const int wr = wid >> 2, wc = wid & 3;     // 2x4 wave grid; wave owns 128x64 of C

  const int bid = blockIdx.x;
  const int swz = (bid & 7) * 32 + (bid >> 3);   // XCD-aware remap (256 = 8*32)
  const int rowBase = (swz >> 4) * 256;
  const int colBase = (swz & 15) * 256;

  // staging source (per-thread, pre-swizzled column so linear LDS dest = swizzled layout)
  const int srow = tid >> 3;                              // 0..63 within a piece
  const int scolb = ((tid & 7) << 4) ^ ((srow & 7) << 4);
  const unsigned short* pA = A + (size_t)(rowBase + srow) * NN + (scolb >> 1);
  const unsigned short* pB = BT + (size_t)(colBase + srow) * NN + (scolb >> 1);

  // ds_read swizzled column constants
  const int rl = lane & 15;
  const int c0 = ((lane >> 4) << 4) ^ ((lane & 7) << 4);  // kk=0 physical col byte
  const int c1 = c0 ^ 64;                                  // kk=1
  const int aoff = (wr * 128 + rl) * 128;          // A row byte base (mh0,m=0)
  const int boff = 32768 + (wc * 64 + rl) * 128;   // B row byte base

  f32x4 acc[8][4] = {};
  bf16x8 bk0[4], bk1[4], afA[4], afB[4];

  // prologue: stage tile0 -> buf0 (A-odd last), preload P1 frags
  {
    char* w0 = smem + (wid << 10);
    GLDS(pB + (size_t)0 * 64 * NN, w0 + 32768 + 0 * 8192);
    GLDS(pB + (size_t)1 * 64 * NN, w0 + 32768 + 1 * 8192);
    GLDS(pB + (size_t)2 * 64 * NN, w0 + 32768 + 2 * 8192);
    GLDS(pB + (size_t)3 * 64 * NN, w0 + 32768 + 3 * 8192);
    GLDS(pA + (size_t)0 * 64 * NN, w0 + 0 * 8192);
    GLDS(pA + (size_t)2 * 64 * NN, w0 + 2 * 8192);
    GLDS(pA + (size_t)1 * 64 * NN, w0 + 1 * 8192);
    GLDS(pA + (size_t)3 * 64 * NN, w0 + 3 * 8192);
    asm volatile("s_waitcnt vmcnt(2)" ::: "memory");
    __builtin_amdgcn_s_barrier();
#pragma unroll
    for (int m = 0; m < 4; ++m) afA[m] = *(const bf16x8*)(smem + aoff + m * 2048 + c0);
#pragma unroll
    for (int n = 0; n < 4; ++n) bk0[n] = *(const bf16x8*)(smem + boff + n * 2048 + c0);
  }

#pragma unroll 2
  for (int t = 0; t < NT; ++t) {
    const char* lb = smem + ((t & 1) << 16);
    char* st = smem + (((t & 1) ^ 1) << 16) + (wid << 10);
    const unsigned short* s1A = pA + ((t + 1) & 63) * 64;
    const unsigned short* s1B = pB + ((t + 1) & 63) * 64;

    // ---- P1: MFMA(mh0,k0) on afA,bk0; prefetch P2 frags; stage B012(t+1) ----
    GLDS(s1B + (size_t)0 * 64 * NN, st + 32768 + 0 * 8192);
    GLDS(s1B + (size_t)1 * 64 * NN, st + 32768 + 1 * 8192);
    GLDS(s1B + (size_t)2 * 64 * NN, st + 32768 + 2 * 8192);
#pragma unroll
    for (int m = 0; m < 4; ++m) afB[m] = *(const bf16x8*)(lb + aoff + m * 2048 + c1);
#pragma unroll
    for (int n = 0; n < 4; ++n) bk1[n] = *(const bf16x8*)(lb + boff + n * 2048 + c1);
    __builtin_amdgcn_s_setprio(1);
#pragma unroll
    for (int m = 0; m < 4; ++m)
#pragma unroll
      for (int n = 0; n < 4; ++n)
        acc[m][n] = __builtin_amdgcn_mfma_f32_16x16x32_bf16(afA[m], bk0[n], acc[m][n], 0, 0, 0);
    __builtin_amdgcn_s_setprio(0);
    asm volatile("s_waitcnt vmcnt(3)" ::: "memory");   // A-odd(t) landed
    __builtin_amdgcn_sched_barrier(0);

    // ---- P2: MFMA(mh0,k1) on afB,bk1; prefetch P3 frags (mh1,k0); stage B3,A0,A2(t+1) ----
    GLDS(s1B + (size_t)3 * 64 * NN, st + 32768 + 3 * 8192);
    GLDS(s1A + (size_t)0 * 64 * NN, st + 0 * 8192);
    GLDS(s1A + (size_t)2 * 64 * NN, st + 2 * 8192);
#pragma unroll
    for (int m = 0; m < 4; ++m) afA[m] = *(const bf16x8*)(lb + aoff + (4 + m) * 2048 + c0);
    __builtin_amdgcn_s_setprio(1);
#pragma unroll
    for (int m = 0; m < 4; ++m)
#pragma unroll
      for (int n = 0; n < 4; ++n)
        acc[m][n] = __builtin_amdgcn_mfma_f32_16x16x32_bf16(afB[m], bk1[n], acc[m][n], 0, 0, 0);
    __builtin_amdgcn_s_setprio(0);
    __builtin_amdgcn_sched_barrier(0);

    // ---- P3: MFMA(mh1,k0) on afA,bk0; prefetch P4 frags (mh1,k1); stage A1,A3(t+1);
    //         tile-end sync moved HERE (no lb reads after this phase) ----
    GLDS(s1A + (size_t)1 * 64 * NN, st + 1 * 8192);
    GLDS(s1A + (size_t)3 * 64 * NN, st + 3 * 8192);
#pragma unroll
    for (int m = 0; m < 4; ++m) afB[m] = *(const bf16x8*)(lb + aoff + (4 + m) * 2048 + c1);
    __builtin_amdgcn_s_setprio(1);
#pragma unroll
    for (int m = 0; m < 4; ++m)
#pragma unroll
      for (int n = 0; n < 4; ++n)
        acc[4 + m][n] = __builtin_amdgcn_mfma_f32_16x16x32_bf16(afA[m], bk0[n], acc[4 + m][n], 0, 0, 0);
    __builtin_amdgcn_s_setprio(0);
    asm volatile("s_waitcnt lgkmcnt(0)" ::: "memory");  // wave's lb reads retired
    asm volatile("s_waitcnt vmcnt(2)" ::: "memory");    // 6 early pieces of t+1 landed
    __builtin_amdgcn_s_barrier();                       // buf reuse fence (1 per tile)
    __builtin_amdgcn_sched_barrier(0);

    // ---- P4: preload next tile's P1 frags (lands under MFMAs); MFMA(mh1,k1) ----
    {
      const char* nb = smem + (((t + 1) & 1) << 16);
#pragma unroll
      for (int m = 0; m < 4; ++m) afA[m] = *(const bf16x8*)(nb + aoff + m * 2048 + c0);
#pragma unroll
      for (int n = 0; n < 4; ++n) bk0[n] = *(const bf16x8*)(nb + boff + n * 2048 + c0);
    }
    __builtin_amdgcn_s_setprio(1);
#pragma unroll
    for (int m = 0; m < 4; ++m)
#pragma unroll
      for (int n = 0; n < 4; ++n)
        acc[4 + m][n] = __builtin_amdgcn_mfma_f32_16x16x32_bf16(afB[m], bk1[n], acc[4 + m][n], 0, 0, 0);
    __builtin_amdgcn_s_setprio(0);
    __builtin_amdgcn_sched_barrier(0);
  }

  // ---- epilogue ----
  const int orow = rowBase + wr * 128 + (lane >> 4) * 4;
  const int ocol = colBase + wc * 64 + (lane & 15);
  if (EPI == 0) {
#pragma unroll
    for (int n = 0; n < 4; ++n) {
      int ccol = ocol + n * 16;
#pragma unroll
      for (int m = 0; m < 8; ++m) {
#pragma unroll
        for (int i = 0; i < 4; ++i) {
          C[(size_t)(orow + m * 16 + i) * NN + ccol] = (unsigned short)f2bf(acc[m][n][i]);
        }
      }
    }
  } else {
    // x1 = sigmoid(acc + b1[col]); h2[row] += sum_col x1*W2[col]
    float bv[4], wv[4];
#pragma unroll
    for (int n = 0; n < 4; ++n) { bv[n] = bias[ocol + n * 16]; wv[n] = W2[ocol + n * 16]; }
#pragma unroll
    for (int m = 0; m < 8; ++m) {
#pragma unroll
      for (int i = 0; i < 4; ++i) {
        float s = 0.0f;
#pragma unroll
        for (int n = 0; n < 4; ++n) {
          float x = 1.0f / (1.0f + __expf(-(acc[m][n][i] + bv[n])));
          s += x * wv[n];
        }
        s += __shfl_xor(s, 1);
        s += __shfl_xor(s, 2);
        s += __shfl_xor(s, 4);
        s += __shfl_xor(s, 8);
        if ((lane & 15) == 0) atomicAdd(&h2[orow + m * 16 + i], s);
      }
    }
  }
}

// ---------------- layer 2 tail ----------------

__global__ void init_t_kernel(const float* __restrict__ dinv, const float* __restrict__ h2,
                              const float* __restrict__ b2, float* __restrict__ tacc) {
  int v = blockIdx.x * 256 + threadIdx.x;
  if (v < NN) tacc[v] = dinv[v] * dinv[v] * h2[v] + b2[0];
}

__global__ void scatter_t_kernel(const int* __restrict__ src, const int* __restrict__ dst,
                                 int E, const float* __restrict__ dinv,
                                 const float* __restrict__ h2, float* __restrict__ tacc) {
  int e = blockIdx.x * 256 + threadIdx.x;
  if (e < E) {
    int s = src[e], d = dst[e];
    atomicAdd(&tacc[d], dinv[s] * dinv[d] * h2[s]);
  }
}

__global__ void final_kernel(const float* __restrict__ tacc, float* __restrict__ out) {
  int v = blockIdx.x * 256 + threadIdx.x;
  if (v < NN) out[v] = 1.0f / (1.0f + __expf(-tacc[v]));
}

// ---------------- launch ----------------

extern "C" void kernel_launch(void* const* d_in, const int* in_sizes, int n_in,
                              void* d_out, int out_size, void* d_ws, size_t ws_size,
                              hipStream_t stream) {
  const float* x  = (const float*)d_in[0];
  const int*   ei = (const int*)d_in[1];
  const float* W1 = (const float*)d_in[2];
  const float* b1 = (const float*)d_in[3];
  const float* W2 = (const float*)d_in[4];
  const float* b2 = (const float*)d_in[5];
  float* out = (float*)d_out;
  const int E = in_sizes[1] / 2;
  const int* esrc = ei;
  const int* edst = ei + E;

  char* w = (char*)d_ws;
  float*          Sf  = (float*)w;                                  // [0,64M) f32 dense S
  unsigned short* H1T = (unsigned short*)w;                         // [0,32M)  (after Sf dead)
  unsigned short* W1T = (unsigned short*)(w + (size_t)(32u << 20)); // [32M,64M)
  unsigned short* Sbf = (unsigned short*)(w + (size_t)(64u << 20)); // [64M,96M)
  unsigned short* Xbf = (unsigned short*)(w + (size_t)(96u << 20)); // [96M,128M)
  float* deg  = (float*)(w + (size_t)(128u << 20));
  float* dinv = deg + 4096;
  float* h2   = deg + 8192;
  float* tacc = deg + 12288;

  // graph normalization
  init_deg_kernel<<<16, 256, 0, stream>>>(deg);
  count_deg_kernel<<<(E + 255) / 256, 256, 0, stream>>>(edst, E, deg);
  dinv_kernel<<<16, 256, 0, stream>>>(deg, dinv);

  // dense S (f32, atomics sum duplicate edges), then cast to bf16
  hipMemsetAsync(Sf, 0, (size_t)64 << 20, stream);
  hipMemsetAsync(h2, 0, 4096 * sizeof(float), stream);
  diag_kernel<<<16, 256, 0, stream>>>(dinv, Sf);
  scatter_S_kernel<<<(E + 255) / 256, 256, 0, stream>>>(esrc, edst, E, dinv, Sf);
  cast_kernel<<<8192, 256, 0, stream>>>(Sf, Sbf, NN * NN);

  // operand preparation
  cast_kernel<<<8192, 256, 0, stream>>>(x, Xbf, NN * NN);
  transpose_cast_kernel<<<dim3(128, 128), dim3(32, 8), 0, stream>>>(W1, W1T);

  // layer 1: GEMM1 (H1T), then GEMM2 with fused sigmoid + W2 matvec -> h2
  gemm256_kernel<0><<<256, 512, 0, stream>>>(W1T, Xbf, H1T, nullptr, nullptr, nullptr);
  gemm256_kernel<1><<<256, 512, 0, stream>>>(Sbf, H1T, nullptr, b1, W2, h2);

  // layer 2 tail: scalar aggregation + sigmoid
  init_t_kernel<<<16, 256, 0, stream>>>(dinv, h2, b2, tacc);
  scatter_t_kernel<<<(E + 255) / 256, 256, 0, stream>>>(esrc, edst, E, dinv, h2, tacc);
  final_kernel<<<16, 256, 0, stream>>>(tacc, out);
}